// Round 4
// baseline (630.794 us; speedup 1.0000x reference)
//
#include <hip/hip_runtime.h>
#include <hip/hip_bf16.h>
#include <hip/hip_cooperative_groups.h>
#include <math.h>

namespace cg = cooperative_groups;

typedef __attribute__((ext_vector_type(8))) short short8;
typedef __attribute__((ext_vector_type(4))) float f32x4;

#define NTHR 256

// ---------- bf16 helpers (RNE) ----------
__device__ __forceinline__ ushort f2bf(float f) {
    uint u = __float_as_uint(f);
    return (ushort)((u + 0x7FFFu + ((u >> 16) & 1u)) >> 16);
}
__device__ __forceinline__ uint pk2bf(float a, float b) {
    return (uint)f2bf(a) | ((uint)f2bf(b) << 16);
}
__device__ __forceinline__ float bfl(uint r) { return __uint_as_float(r << 16); }
__device__ __forceinline__ float bfh(uint r) { return __uint_as_float(r & 0xFFFF0000u); }

struct Params {
    const float* x; const float* dis;
    const float* W1; const float* b1;
    const float* W2; const float* b2;
    const float* W3; const float* b3;
    const float* Wout; const float* bout;
    const int* src; const int* dst; const int* ti;
    float* out;
    uint* degOut; uint* degIn;
    float* normOut; float* normIn;
    int* rowPtr; int* fill;
    uint* edge;
    ushort* xbf; ushort* w1bf; ushort* w2bf; ushort* w3bf;
    ushort* bufA; ushort* bufB;
    float* av; float* bv;
    int N, E, P;
};

// ================= device phase functions (grid-stride; any grid size) =================

__device__ void phase_zero_cvt(const Params& p) {
    int gtid = blockIdx.x * NTHR + threadIdx.x;
    int GSZ = gridDim.x * NTHR;
    for (int i = gtid; i < p.N; i += GSZ) {
        p.degOut[i] = 0u;
        p.degIn[i] = 0u;
    }
    const int nx = p.N * 128;
    const int n1 = 128 * 256, n2 = 256 * 256, n3 = 256 * 64;
    const int tot4 = (nx + n1 + n2 + n3) >> 2;
    for (int i4 = gtid; i4 < tot4; i4 += GSZ) {
        int i = i4 * 4;
        const float* s;
        ushort* d;
        int off;
        if (i < nx) { s = p.x; d = p.xbf; off = i; }
        else if (i < nx + n1) { s = p.W1; d = p.w1bf; off = i - nx; }
        else if (i < nx + n1 + n2) { s = p.W2; d = p.w2bf; off = i - nx - n1; }
        else { s = p.W3; d = p.w3bf; off = i - nx - n1 - n2; }
        float4 v = *(const float4*)&s[off];
        uint2 pkv;
        pkv.x = pk2bf(v.x, v.y);
        pkv.y = pk2bf(v.z, v.w);
        *(uint2*)&d[off] = pkv;
    }
}

__device__ void phase_deg(const Params& p) {
    int gtid = blockIdx.x * NTHR + threadIdx.x;
    int GSZ = gridDim.x * NTHR;
    for (int e = gtid; e < p.E; e += GSZ) {
        atomicAdd(&p.degOut[p.src[e]], 1u);
        atomicAdd(&p.degIn[p.dst[e]], 1u);
    }
}

// block 0: serial-scan degIn -> rowPtr/fill (needs blockDim == NTHR, N <= NTHR*40)
// blocks 1..: norms. `part` must be >= NTHR ints of LDS.
__device__ void phase_scan_norm(const Params& p, int* part) {
    int tid = threadIdx.x;
    if (blockIdx.x == 0) {
        const int CH = 40;  // 256*40 = 10240 >= N
        int base = tid * CH;
        int s = 0;
        for (int i = 0; i < CH; ++i) {
            int idx = base + i;
            if (idx < p.N) s += (int)p.degIn[idx];
        }
        part[tid] = s;
        __syncthreads();
        for (int off = 1; off < NTHR; off <<= 1) {
            int v = (tid >= off) ? part[tid - off] : 0;
            __syncthreads();
            part[tid] += v;
            __syncthreads();
        }
        int run = tid ? part[tid - 1] : 0;
        for (int i = 0; i < CH; ++i) {
            int idx = base + i;
            if (idx < p.N) {
                p.rowPtr[idx] = run;
                p.fill[idx] = run;
                run += (int)p.degIn[idx];
            }
        }
        if (tid == NTHR - 1) p.rowPtr[p.N] = run;
    } else {
        for (int i = (blockIdx.x - 1) * NTHR + tid; i < p.N; i += (gridDim.x - 1) * NTHR) {
            uint d0 = p.degOut[i];
            uint d1 = p.degIn[i];
            p.normOut[i] = d0 ? rsqrtf((float)d0) : 0.f;
            p.normIn[i] = d1 ? rsqrtf((float)d1) : 0.f;
        }
    }
}

__device__ void phase_scatter(const Params& p) {
    int gtid = blockIdx.x * NTHR + threadIdx.x;
    int GSZ = gridDim.x * NTHR;
    for (int e = gtid; e < p.E; e += GSZ) {
        int s = p.src[e];
        int v = p.dst[e];
        int pos = atomicAdd(&p.fill[v], 1);
        p.edge[pos] = (uint)s | ((uint)f2bf(p.normOut[s]) << 16);
    }
}

// gather element type per V = D/64
template <int V> struct GT;
template <> struct GT<1> { using T = ushort; };
template <> struct GT<2> { using T = uint; };
template <> struct GT<4> { using T = uint2; };

template <int D>
__device__ __forceinline__ void accum(float* acc, float w, typename GT<D / 64>::T g) {
    constexpr int V = D / 64;
    if constexpr (V == 1) {
        acc[0] = fmaf(w, bfl((uint)g), acc[0]);
    } else if constexpr (V == 2) {
        acc[0] = fmaf(w, bfl(g), acc[0]);
        acc[1] = fmaf(w, bfh(g), acc[1]);
    } else {
        acc[0] = fmaf(w, bfl(g.x), acc[0]);
        acc[1] = fmaf(w, bfh(g.x), acc[1]);
        acc[2] = fmaf(w, bfl(g.y), acc[2]);
        acc[3] = fmaf(w, bfh(g.y), acc[3]);
    }
}

// 1 wave per node, grid-stride.
// ACT==0: outb[v][c] = bf16( normIn[v] * sum_e w_e * h[s_e][c] )
// ACT==2: g = sigmoid(normIn[v]*sum + b3[c]); av[v]=g.WoutA, bv[v]=g.WoutB
template <int D, int ACT>
__device__ void agg_phase(const Params& p, const ushort* __restrict__ h,
                          ushort* __restrict__ outb) {
    constexpr int V = D / 64;
    using T = typename GT<V>::T;
    int nwaves = (gridDim.x * NTHR) >> 6;
    int wid = (blockIdx.x * NTHR + threadIdx.x) >> 6;
    int l = threadIdx.x & 63;
    const ushort* hb = h + l * V;

    for (int v = wid; v < p.N; v += nwaves) {
        int beg = p.rowPtr[v];
        int end = p.rowPtr[v + 1];
        float acc[V] = {};
        int e = beg;

        if (e + 8 <= end) {
            uint w[8];
#pragma unroll
            for (int j = 0; j < 8; ++j) w[j] = p.edge[e + j];
            for (;;) {
                T g[8];
#pragma unroll
                for (int j = 0; j < 8; ++j) g[j] = *(const T*)&hb[(w[j] & 0xFFFFu) * D];
                e += 8;
                bool more = (e + 8 <= end);
                uint wn[8];
                if (more) {
#pragma unroll
                    for (int j = 0; j < 8; ++j) wn[j] = p.edge[e + j];
                }
#pragma unroll
                for (int j = 0; j < 8; ++j) accum<D>(acc, bfh(w[j]), g[j]);
                if (!more) break;
#pragma unroll
                for (int j = 0; j < 8; ++j) w[j] = wn[j];
            }
        }
        for (; e < end; ++e) {
            uint ew = p.edge[e];
            T gg = *(const T*)&hb[(ew & 0xFFFFu) * D];
            accum<D>(acc, bfh(ew), gg);
        }

        float nin = p.normIn[v];
        if constexpr (ACT == 0) {
            if constexpr (V == 1) {
                outb[v * D + l] = f2bf(acc[0] * nin);
            } else if constexpr (V == 2) {
                *(uint*)&outb[v * D + l * 2] = pk2bf(acc[0] * nin, acc[1] * nin);
            } else {
                uint2 pkv;
                pkv.x = pk2bf(acc[0] * nin, acc[1] * nin);
                pkv.y = pk2bf(acc[2] * nin, acc[3] * nin);
                *(uint2*)&outb[v * D + l * 4] = pkv;
            }
        } else {
            float g = acc[0] * nin + p.b3[l];
            g = 1.f / (1.f + __expf(-g));
            float pa = g * p.Wout[l];
            float pb = g * p.Wout[64 + l];
#pragma unroll
            for (int off = 32; off > 0; off >>= 1) {
                pa += __shfl_down(pa, off);
                pb += __shfl_down(pb, off);
            }
            if (l == 0) {
                p.av[v] = pa;
                p.bv[v] = pb;
            }
        }
    }
}

// MFMA GEMM: C[M,Nn] = A[M,K] @ B[K,Nn] (+bias, relu). Needs BM*40 + 64*40 ushorts of LDS.
template <int BM>
__device__ void gemm_phase(const ushort* __restrict__ A, const ushort* __restrict__ Bw,
                           const float* __restrict__ bias, ushort* __restrict__ C,
                           int M, int K, int Nn, bool relu,
                           ushort* sAp, ushort* sBp) {
    constexpr int WR = BM / 64;
    int tid = threadIdx.x;
    int wave = tid >> 6;
    int lane = tid & 63;
    int l15 = lane & 15;
    int l4 = lane >> 4;
    int tiles_n = Nn >> 6;
    int ntiles = ((M + BM - 1) / BM) * tiles_n;

    for (int t = blockIdx.x; t < ntiles; t += gridDim.x) {
        int m0 = (t / tiles_n) * BM;
        int n0 = (t % tiles_n) * 64;
        f32x4 acc[WR][4] = {};

        for (int k0 = 0; k0 < K; k0 += 32) {
#pragma unroll
            for (int pp = 0; pp < BM / 64; ++pp) {
                int idx = pp * 256 + tid;
                int row = idx >> 2;
                int c8 = (idx & 3) * 8;
                short8 val = {};
                int grow = m0 + row;
                if (grow < M) val = *(const short8*)&A[(size_t)grow * K + k0 + c8];
                *(short8*)&sAp[row * 40 + c8] = val;
            }
            {
                int k = tid & 31;
                int n8 = (tid >> 5) * 8;
                short8 val = *(const short8*)&Bw[(size_t)(k0 + k) * Nn + n0 + n8];
#pragma unroll
                for (int j = 0; j < 8; ++j) sBp[(n8 + j) * 40 + k] = (ushort)val[j];
            }
            __syncthreads();

            short8 bf[4];
#pragma unroll
            for (int n = 0; n < 4; ++n)
                bf[n] = *(const short8*)&sBp[(n * 16 + l15) * 40 + l4 * 8];
#pragma unroll
            for (int r = 0; r < WR; ++r) {
                short8 af = *(const short8*)&sAp[(wave * (16 * WR) + r * 16 + l15) * 40 + l4 * 8];
#pragma unroll
                for (int n = 0; n < 4; ++n)
                    acc[r][n] = __builtin_amdgcn_mfma_f32_16x16x32_bf16(af, bf[n], acc[r][n], 0, 0, 0);
            }
            __syncthreads();
        }

#pragma unroll
        for (int r = 0; r < WR; ++r) {
            int rowb = m0 + wave * (16 * WR) + r * 16 + l4 * 4;
#pragma unroll
            for (int n = 0; n < 4; ++n) {
                int col = n0 + n * 16 + l15;
                float bsv = bias ? bias[col] : 0.f;
#pragma unroll
                for (int q = 0; q < 4; ++q) {
                    int row = rowb + q;
                    if (row < M) {
                        float vv = acc[r][n][q] + bsv;
                        if (relu) vv = fmaxf(vv, 0.f);
                        C[(size_t)row * Nn + col] = f2bf(vv);
                    }
                }
            }
        }
    }
}

__device__ void phase_final(const Params& p) {
    int gtid = blockIdx.x * NTHR + threadIdx.x;
    int GSZ = gridDim.x * NTHR;
    float w128 = p.Wout[128];
    float b0 = p.bout[0];
    for (int i = gtid; i < p.P; i += GSZ) {
        int o = p.ti[i];
        int d = p.ti[p.P + i];
        float s = p.av[o] + p.bv[d] + p.dis[(size_t)o * p.N + d] * w128 + b0;
        p.out[i] = tanhf(s);
    }
}

// ================= cooperative mega-kernel =================
__global__ __launch_bounds__(NTHR, 4) void mega(Params p) {
    cg::grid_group grid = cg::this_grid();
    __shared__ ushort sA[128 * 40];
    __shared__ ushort sB[64 * 40];

    phase_zero_cvt(p);
    grid.sync();
    phase_deg(p);
    grid.sync();
    phase_scan_norm(p, (int*)sA);
    grid.sync();
    phase_scatter(p);
    grid.sync();
    agg_phase<128, 0>(p, p.xbf, p.bufA);
    grid.sync();
    gemm_phase<128>(p.bufA, p.w1bf, p.b1, p.bufB, p.N, 128, 256, true, sA, sB);
    grid.sync();
    agg_phase<256, 0>(p, p.bufB, p.bufA);
    grid.sync();
    gemm_phase<128>(p.bufA, p.w2bf, p.b2, p.bufB, p.N, 256, 256, true, sA, sB);
    grid.sync();
    gemm_phase<64>(p.bufB, p.w3bf, nullptr, p.bufA, p.N, 256, 64, false, sA, sB);
    grid.sync();
    agg_phase<64, 2>(p, p.bufA, nullptr);
    grid.sync();
    phase_final(p);
}

// ================= fallback per-phase kernels =================
__global__ __launch_bounds__(NTHR) void k_p0(Params p) { phase_zero_cvt(p); }
__global__ __launch_bounds__(NTHR) void k_p1(Params p) { phase_deg(p); }
__global__ __launch_bounds__(NTHR) void k_p2(Params p) {
    __shared__ int part[NTHR];
    phase_scan_norm(p, part);
}
__global__ __launch_bounds__(NTHR) void k_p3(Params p) { phase_scatter(p); }
template <int D, int ACT>
__global__ __launch_bounds__(NTHR) void k_agg(Params p, const ushort* h, ushort* outb) {
    agg_phase<D, ACT>(p, h, outb);
}
__global__ __launch_bounds__(NTHR) void k_gemm1(Params p) {
    __shared__ ushort sA[128 * 40];
    __shared__ ushort sB[64 * 40];
    gemm_phase<128>(p.bufA, p.w1bf, p.b1, p.bufB, p.N, 128, 256, true, sA, sB);
}
__global__ __launch_bounds__(NTHR) void k_gemm2(Params p) {
    __shared__ ushort sA[128 * 40];
    __shared__ ushort sB[64 * 40];
    gemm_phase<128>(p.bufA, p.w2bf, p.b2, p.bufB, p.N, 256, 256, true, sA, sB);
}
__global__ __launch_bounds__(NTHR) void k_gemm3(Params p) {
    __shared__ ushort sA[64 * 40];
    __shared__ ushort sB[64 * 40];
    gemm_phase<64>(p.bufB, p.w3bf, nullptr, p.bufA, p.N, 256, 64, false, sA, sB);
}
__global__ __launch_bounds__(NTHR) void k_final(Params p) { phase_final(p); }

extern "C" void kernel_launch(void* const* d_in, const int* in_sizes, int n_in,
                              void* d_out, int out_size, void* d_ws, size_t ws_size,
                              hipStream_t stream) {
    Params prm;
    prm.x    = (const float*)d_in[0];
    prm.dis  = (const float*)d_in[1];
    prm.W1   = (const float*)d_in[2];
    prm.b1   = (const float*)d_in[3];
    prm.W2   = (const float*)d_in[4];
    prm.b2   = (const float*)d_in[5];
    prm.W3   = (const float*)d_in[6];
    prm.b3   = (const float*)d_in[7];
    prm.Wout = (const float*)d_in[8];
    prm.bout = (const float*)d_in[9];
    prm.src  = (const int*)d_in[10];
    prm.dst  = (const int*)d_in[11];
    prm.ti   = (const int*)d_in[12];
    prm.out  = (float*)d_out;

    const int IN = 128, HID = 256, EMB = 64;
    prm.N = in_sizes[0] / IN;
    prm.E = in_sizes[10];
    prm.P = in_sizes[12] / 2;
    const int N = prm.N, E = prm.E, P = prm.P;

    char* ws = (char*)d_ws;
    size_t off = 0;
    auto alloc = [&](size_t bytes) {
        size_t o = off;
        off = (off + bytes + 255) & ~(size_t)255;
        return o;
    };
    size_t o_degO  = alloc((size_t)N * 4);
    size_t o_degI  = alloc((size_t)N * 4);
    size_t o_nrmO  = alloc((size_t)N * 4);
    size_t o_nrmI  = alloc((size_t)N * 4);
    size_t o_rowP  = alloc((size_t)(N + 1) * 4);
    size_t o_fill  = alloc((size_t)N * 4);
    size_t o_edge  = alloc((size_t)E * 4);
    size_t o_xbf   = alloc((size_t)N * IN * 2);
    size_t o_w1    = alloc((size_t)IN * HID * 2);
    size_t o_w2    = alloc((size_t)HID * HID * 2);
    size_t o_w3    = alloc((size_t)HID * EMB * 2);
    size_t o_bufA  = alloc((size_t)N * HID * 2);
    size_t o_bufB  = alloc((size_t)N * HID * 2);
    size_t o_av    = alloc((size_t)N * 4);
    size_t o_bv    = alloc((size_t)N * 4);
    (void)ws_size;

    prm.degOut  = (uint*)(ws + o_degO);
    prm.degIn   = (uint*)(ws + o_degI);
    prm.normOut = (float*)(ws + o_nrmO);
    prm.normIn  = (float*)(ws + o_nrmI);
    prm.rowPtr  = (int*)(ws + o_rowP);
    prm.fill    = (int*)(ws + o_fill);
    prm.edge    = (uint*)(ws + o_edge);
    prm.xbf     = (ushort*)(ws + o_xbf);
    prm.w1bf    = (ushort*)(ws + o_w1);
    prm.w2bf    = (ushort*)(ws + o_w2);
    prm.w3bf    = (ushort*)(ws + o_w3);
    prm.bufA    = (ushort*)(ws + o_bufA);
    prm.bufB    = (ushort*)(ws + o_bufB);
    prm.av      = (float*)(ws + o_av);
    prm.bv      = (float*)(ws + o_bv);

    // ---- try cooperative mega-kernel with runtime-queried capacity ----
    bool coop_ok = false;
    {
        int dev = 0;
        (void)hipGetDevice(&dev);
        int numCU = 0;
        (void)hipDeviceGetAttribute(&numCU, hipDeviceAttributeMultiprocessorCount, dev);
        int maxBlk = 0;
        hipError_t qe = hipOccupancyMaxActiveBlocksPerMultiprocessor(
            &maxBlk, (const void*)mega, NTHR, 0);
        if (qe == hipSuccess && maxBlk > 0 && numCU > 0) {
            long long g = (long long)maxBlk * numCU;
            int grid = (g > 2048) ? 2048 : (int)g;
            if (grid >= 2) {
                void* args[] = {&prm};
                hipError_t le = hipLaunchCooperativeKernel((const void*)mega, dim3(grid),
                                                           dim3(NTHR), args, 0, stream);
                if (le == hipSuccess) {
                    coop_ok = true;
                } else {
                    (void)hipGetLastError();  // clear sticky error
                }
            }
        } else {
            (void)hipGetLastError();
        }
    }

    // ---- fallback: identical phases as separate dispatches ----
    if (!coop_ok) {
        k_p0<<<1024, NTHR, 0, stream>>>(prm);
        k_p1<<<1024, NTHR, 0, stream>>>(prm);
        k_p2<<<256, NTHR, 0, stream>>>(prm);
        k_p3<<<1024, NTHR, 0, stream>>>(prm);
        k_agg<128, 0><<<1024, NTHR, 0, stream>>>(prm, prm.xbf, prm.bufA);
        k_gemm1<<<320, NTHR, 0, stream>>>(prm);
        k_agg<256, 0><<<1024, NTHR, 0, stream>>>(prm, prm.bufB, prm.bufA);
        k_gemm2<<<320, NTHR, 0, stream>>>(prm);
        k_gemm3<<<160, NTHR, 0, stream>>>(prm);
        k_agg<64, 2><<<1024, NTHR, 0, stream>>>(prm, prm.bufA, nullptr);
        k_final<<<1954, NTHR, 0, stream>>>(prm);
    }
}

// Round 5
// 246.174 us; speedup vs baseline: 2.5624x; 2.5624x over previous
//
#include <hip/hip_runtime.h>
#include <math.h>

typedef __attribute__((ext_vector_type(8))) short short8;
typedef __attribute__((ext_vector_type(4))) float f32x4;

#define NTHR 256

// ---------- bf16 helpers (RNE) ----------
__device__ __forceinline__ ushort f2bf(float f) {
    uint u = __float_as_uint(f);
    return (ushort)((u + 0x7FFFu + ((u >> 16) & 1u)) >> 16);
}
__device__ __forceinline__ uint pk2bf(float a, float b) {
    return (uint)f2bf(a) | ((uint)f2bf(b) << 16);
}
__device__ __forceinline__ float bfl(uint r) { return __uint_as_float(r << 16); }
__device__ __forceinline__ float bfh(uint r) { return __uint_as_float(r & 0xFFFF0000u); }

struct Params {
    const float* x; const float* dis;
    const float* W1; const float* b1;
    const float* W2; const float* b2;
    const float* W3; const float* b3;
    const float* Wout; const float* bout;
    const int* src; const int* dst; const int* ti;
    float* out;
    uint* degOut; uint* degIn;
    float* normOut; float* normIn;
    int* rowPtr; int* fill;
    uint* edge;
    ushort* xbf; ushort* w1bf; ushort* w2bf; ushort* w3bf;
    ushort* bufA; ushort* bufB;
    float* av; float* bv;
    int N, E, P, Ecap;
};

// ---------------- k_pre: zero deg counters, zero edge buffer, fp32->bf16 cvt ----------
__global__ __launch_bounds__(NTHR) void k_pre(Params p) {
    int gtid = blockIdx.x * NTHR + threadIdx.x;
    int GSZ = gridDim.x * NTHR;
    for (int i = gtid; i < p.N; i += GSZ) {
        p.degOut[i] = 0u;
        p.degIn[i] = 0u;
    }
    for (int i = gtid; i < p.Ecap; i += GSZ) p.edge[i] = 0u;
    const int nx = p.N * 128;
    const int n1 = 128 * 256, n2 = 256 * 256, n3 = 256 * 64;
    const int tot4 = (nx + n1 + n2 + n3) >> 2;
    for (int i4 = gtid; i4 < tot4; i4 += GSZ) {
        int i = i4 * 4;
        const float* s;
        ushort* d;
        int off;
        if (i < nx) { s = p.x; d = p.xbf; off = i; }
        else if (i < nx + n1) { s = p.W1; d = p.w1bf; off = i - nx; }
        else if (i < nx + n1 + n2) { s = p.W2; d = p.w2bf; off = i - nx - n1; }
        else { s = p.W3; d = p.w3bf; off = i - nx - n1 - n2; }
        float4 v = *(const float4*)&s[off];
        uint2 pkv;
        pkv.x = pk2bf(v.x, v.y);
        pkv.y = pk2bf(v.z, v.w);
        *(uint2*)&d[off] = pkv;
    }
}

// ---------------- k_deg ----------------
__global__ __launch_bounds__(NTHR) void k_deg(Params p) {
    int e = blockIdx.x * NTHR + threadIdx.x;
    if (e < p.E) {
        atomicAdd(&p.degOut[p.src[e]], 1u);
        atomicAdd(&p.degIn[p.dst[e]], 1u);
    }
}

// ---------------- k_scan_norm: block 0 scans PADDED degIn; others compute norms -------
__global__ __launch_bounds__(NTHR) void k_scan_norm(Params p) {
    __shared__ int part[NTHR];
    int tid = threadIdx.x;
    if (blockIdx.x == 0) {
        const int CH = 40;  // 256*40 = 10240 >= N
        int base = tid * CH;
        int s = 0;
        for (int i = 0; i < CH; ++i) {
            int idx = base + i;
            if (idx < p.N) s += ((int)p.degIn[idx] + 7) & ~7;
        }
        part[tid] = s;
        __syncthreads();
        for (int off = 1; off < NTHR; off <<= 1) {
            int v = (tid >= off) ? part[tid - off] : 0;
            __syncthreads();
            part[tid] += v;
            __syncthreads();
        }
        int run = tid ? part[tid - 1] : 0;
        for (int i = 0; i < CH; ++i) {
            int idx = base + i;
            if (idx < p.N) {
                p.rowPtr[idx] = run;
                p.fill[idx] = run;
                run += ((int)p.degIn[idx] + 7) & ~7;
            }
        }
        if (tid == NTHR - 1) p.rowPtr[p.N] = run;
    } else {
        for (int i = (blockIdx.x - 1) * NTHR + tid; i < p.N; i += (gridDim.x - 1) * NTHR) {
            uint d0 = p.degOut[i];
            uint d1 = p.degIn[i];
            p.normOut[i] = d0 ? rsqrtf((float)d0) : 0.f;
            p.normIn[i] = d1 ? rsqrtf((float)d1) : 0.f;
        }
    }
}

// ---------------- k_scatter: counting sort; pack (src | bf16(normOut[src])<<16) -------
__global__ __launch_bounds__(NTHR) void k_scatter(Params p) {
    int e = blockIdx.x * NTHR + threadIdx.x;
    if (e < p.E) {
        int s = p.src[e];
        int v = p.dst[e];
        int pos = atomicAdd(&p.fill[v], 1);
        p.edge[pos] = (uint)s | ((uint)f2bf(p.normOut[s]) << 16);
    }
}

// ---------------- aggregation ----------------
template <int V> struct GT;
template <> struct GT<1> { using T = ushort; };
template <> struct GT<2> { using T = uint; };

template <int V>
__device__ __forceinline__ void accum(float* acc, float w, typename GT<V>::T g) {
    if constexpr (V == 1) {
        acc[0] = fmaf(w, bfl((uint)g), acc[0]);
    } else {
        acc[0] = fmaf(w, bfl(g), acc[0]);
        acc[1] = fmaf(w, bfh(g), acc[1]);
    }
}

// SPLIT waves per node; wave `half` owns channels [half*64*V, (half+1)*64*V).
// Edge segments are padded to multiples of 8 with zero-weight entries.
// ACT==0 (V==2): outb[v][...] = bf16(normIn[v] * sum)
// ACT==2 (V==1): g = sigmoid(sum*normIn + b3[l]); av[v]=g.WoutA, bv[v]=g.WoutB
template <int D, int SPLIT, int ACT>
__global__ __launch_bounds__(NTHR) void k_agg(Params p, const ushort* __restrict__ h,
                                              ushort* __restrict__ outb) {
    constexpr int V = D / (64 * SPLIT);
    using T = typename GT<V>::T;
    int wib = threadIdx.x >> 6;
    int b = blockIdx.x;
    int v, half;
    if constexpr (SPLIT == 2) {
        half = b & 1;             // XCD-parity: even blocks -> half 0, odd -> half 1
        v = (b >> 1) * 4 + wib;
    } else {
        half = 0;
        v = b * 4 + wib;
    }
    if (v >= p.N) return;
    int l = threadIdx.x & 63;
    const ushort* hb = h + half * (64 * V) + l * V;

    int beg = p.rowPtr[v];
    int end = p.rowPtr[v + 1];
    float acc[V] = {};

    if (beg < end) {
        const uint* ep = p.edge;
        uint4 eA = *(const uint4*)(ep + beg);
        uint4 eB = *(const uint4*)(ep + beg + 4);
        int e = beg + 8;
        for (;;) {
            uint w0 = eA.x, w1 = eA.y, w2 = eA.z, w3 = eA.w;
            uint w4 = eB.x, w5 = eB.y, w6 = eB.z, w7 = eB.w;
            T g0 = *(const T*)&hb[(w0 & 0xFFFFu) * D];
            T g1 = *(const T*)&hb[(w1 & 0xFFFFu) * D];
            T g2 = *(const T*)&hb[(w2 & 0xFFFFu) * D];
            T g3 = *(const T*)&hb[(w3 & 0xFFFFu) * D];
            T g4 = *(const T*)&hb[(w4 & 0xFFFFu) * D];
            T g5 = *(const T*)&hb[(w5 & 0xFFFFu) * D];
            T g6 = *(const T*)&hb[(w6 & 0xFFFFu) * D];
            T g7 = *(const T*)&hb[(w7 & 0xFFFFu) * D];
            bool more = e < end;
            uint4 nA, nB;
            if (more) {
                nA = *(const uint4*)(ep + e);
                nB = *(const uint4*)(ep + e + 4);
            }
            accum<V>(acc, bfh(w0), g0);
            accum<V>(acc, bfh(w1), g1);
            accum<V>(acc, bfh(w2), g2);
            accum<V>(acc, bfh(w3), g3);
            accum<V>(acc, bfh(w4), g4);
            accum<V>(acc, bfh(w5), g5);
            accum<V>(acc, bfh(w6), g6);
            accum<V>(acc, bfh(w7), g7);
            if (!more) break;
            eA = nA;
            eB = nB;
            e += 8;
        }
    }

    float nin = p.normIn[v];
    if constexpr (ACT == 0) {
        static_assert(V == 2, "ACT0 expects V==2");
        *(uint*)&outb[(size_t)v * D + half * (64 * V) + l * V] =
            pk2bf(acc[0] * nin, acc[1] * nin);
    } else {
        float g = acc[0] * nin + p.b3[l];
        g = 1.f / (1.f + __expf(-g));
        float pa = g * p.Wout[l];
        float pb = g * p.Wout[64 + l];
#pragma unroll
        for (int off = 32; off > 0; off >>= 1) {
            pa += __shfl_down(pa, off);
            pb += __shfl_down(pb, off);
        }
        if (l == 0) {
            p.av[v] = pa;
            p.bv[v] = pb;
        }
    }
}

// ---------------- bf16 MFMA GEMM (R2-proven) ----------------
template <int BM, int ACT, bool BIAS>
__global__ __launch_bounds__(256) void gemm_bf16(const ushort* __restrict__ A,
                                                 const ushort* __restrict__ B,
                                                 const float* __restrict__ bias,
                                                 ushort* __restrict__ C,
                                                 int M, int K, int N) {
    constexpr int WR = BM / 64;
    __shared__ ushort As[BM * 40];
    __shared__ ushort Bs[64 * 40];

    int tid = threadIdx.x;
    int wave = tid >> 6;
    int lane = tid & 63;
    int l15 = lane & 15;
    int l4 = lane >> 4;
    int m0 = blockIdx.x * BM;
    int n0 = blockIdx.y * 64;

    f32x4 acc[WR][4] = {};

    for (int k0 = 0; k0 < K; k0 += 32) {
#pragma unroll
        for (int pp = 0; pp < BM / 64; ++pp) {
            int idx = pp * 256 + tid;
            int row = idx >> 2;
            int c8 = (idx & 3) * 8;
            short8 val = {};
            int grow = m0 + row;
            if (grow < M) val = *(const short8*)&A[(size_t)grow * K + k0 + c8];
            *(short8*)&As[row * 40 + c8] = val;
        }
        {
            int k = tid & 31;
            int n8 = (tid >> 5) * 8;
            short8 val = *(const short8*)&B[(size_t)(k0 + k) * N + n0 + n8];
#pragma unroll
            for (int j = 0; j < 8; ++j) Bs[(n8 + j) * 40 + k] = (ushort)val[j];
        }
        __syncthreads();

        short8 bf[4];
#pragma unroll
        for (int n = 0; n < 4; ++n)
            bf[n] = *(const short8*)&Bs[(n * 16 + l15) * 40 + l4 * 8];
#pragma unroll
        for (int r = 0; r < WR; ++r) {
            short8 af = *(const short8*)&As[(wave * (16 * WR) + r * 16 + l15) * 40 + l4 * 8];
#pragma unroll
            for (int n = 0; n < 4; ++n)
                acc[r][n] = __builtin_amdgcn_mfma_f32_16x16x32_bf16(af, bf[n], acc[r][n], 0, 0, 0);
        }
        __syncthreads();
    }

#pragma unroll
    for (int r = 0; r < WR; ++r) {
        int rowb = m0 + wave * (16 * WR) + r * 16 + l4 * 4;
#pragma unroll
        for (int n = 0; n < 4; ++n) {
            int col = n0 + n * 16 + l15;
            float bsv = BIAS ? bias[col] : 0.f;
#pragma unroll
            for (int q = 0; q < 4; ++q) {
                int row = rowb + q;
                if (row < M) {
                    float vv = acc[r][n][q] + bsv;
                    if (ACT == 1) vv = fmaxf(vv, 0.f);
                    C[(size_t)row * N + col] = f2bf(vv);
                }
            }
        }
    }
}

// ---------------- final gather + tanh ----------------
__global__ __launch_bounds__(NTHR) void k_final(Params p) {
    int i = blockIdx.x * NTHR + threadIdx.x;
    if (i >= p.P) return;
    int o = p.ti[i];
    int d = p.ti[p.P + i];
    float s = p.av[o] + p.bv[d] + p.dis[(size_t)o * p.N + d] * p.Wout[128] + p.bout[0];
    p.out[i] = tanhf(s);
}

extern "C" void kernel_launch(void* const* d_in, const int* in_sizes, int n_in,
                              void* d_out, int out_size, void* d_ws, size_t ws_size,
                              hipStream_t stream) {
    Params prm;
    prm.x    = (const float*)d_in[0];
    prm.dis  = (const float*)d_in[1];
    prm.W1   = (const float*)d_in[2];
    prm.b1   = (const float*)d_in[3];
    prm.W2   = (const float*)d_in[4];
    prm.b2   = (const float*)d_in[5];
    prm.W3   = (const float*)d_in[6];
    prm.b3   = (const float*)d_in[7];
    prm.Wout = (const float*)d_in[8];
    prm.bout = (const float*)d_in[9];
    prm.src  = (const int*)d_in[10];
    prm.dst  = (const int*)d_in[11];
    prm.ti   = (const int*)d_in[12];
    prm.out  = (float*)d_out;

    const int IN = 128, HID = 256, EMB = 64;
    prm.N = in_sizes[0] / IN;
    prm.E = in_sizes[10];
    prm.P = in_sizes[12] / 2;
    prm.Ecap = prm.E + 8 * prm.N + 8;
    const int N = prm.N, E = prm.E, P = prm.P;

    char* ws = (char*)d_ws;
    size_t off = 0;
    auto alloc = [&](size_t bytes) {
        size_t o = off;
        off = (off + bytes + 255) & ~(size_t)255;
        return o;
    };
    size_t o_degO = alloc((size_t)N * 4);
    size_t o_degI = alloc((size_t)N * 4);
    size_t o_nrmO = alloc((size_t)N * 4);
    size_t o_nrmI = alloc((size_t)N * 4);
    size_t o_rowP = alloc((size_t)(N + 1) * 4);
    size_t o_fill = alloc((size_t)N * 4);
    size_t o_edge = alloc((size_t)prm.Ecap * 4);
    size_t o_xbf  = alloc((size_t)N * IN * 2);
    size_t o_w1   = alloc((size_t)IN * HID * 2);
    size_t o_w2   = alloc((size_t)HID * HID * 2);
    size_t o_w3   = alloc((size_t)HID * EMB * 2);
    size_t o_bufA = alloc((size_t)N * HID * 2);
    size_t o_bufB = alloc((size_t)N * HID * 2);
    size_t o_av   = alloc((size_t)N * 4);
    size_t o_bv   = alloc((size_t)N * 4);
    (void)ws_size;

    prm.degOut  = (uint*)(ws + o_degO);
    prm.degIn   = (uint*)(ws + o_degI);
    prm.normOut = (float*)(ws + o_nrmO);
    prm.normIn  = (float*)(ws + o_nrmI);
    prm.rowPtr  = (int*)(ws + o_rowP);
    prm.fill    = (int*)(ws + o_fill);
    prm.edge    = (uint*)(ws + o_edge);
    prm.xbf     = (ushort*)(ws + o_xbf);
    prm.w1bf    = (ushort*)(ws + o_w1);
    prm.w2bf    = (ushort*)(ws + o_w2);
    prm.w3bf    = (ushort*)(ws + o_w3);
    prm.bufA    = (ushort*)(ws + o_bufA);
    prm.bufB    = (ushort*)(ws + o_bufB);
    prm.av      = (float*)(ws + o_av);
    prm.bv      = (float*)(ws + o_bv);

    k_pre<<<1024, NTHR, 0, stream>>>(prm);
    k_deg<<<(E + NTHR - 1) / NTHR, NTHR, 0, stream>>>(prm);
    k_scan_norm<<<256, NTHR, 0, stream>>>(prm);
    k_scatter<<<(E + NTHR - 1) / NTHR, NTHR, 0, stream>>>(prm);

    int nb4 = (N + 3) / 4;  // blocks for 1 wave/node
    k_agg<128, 1, 0><<<nb4, NTHR, 0, stream>>>(prm, prm.xbf, prm.bufA);
    {
        dim3 grid((N + 127) / 128, HID / 64);
        gemm_bf16<128, 1, true><<<grid, 256, 0, stream>>>(prm.bufA, prm.w1bf, prm.b1, prm.bufB,
                                                          N, IN, HID);
    }
    k_agg<256, 2, 0><<<nb4 * 2, NTHR, 0, stream>>>(prm, prm.bufB, prm.bufA);
    {
        dim3 grid((N + 127) / 128, HID / 64);
        gemm_bf16<128, 1, true><<<grid, 256, 0, stream>>>(prm.bufA, prm.w2bf, prm.b2, prm.bufB,
                                                          N, HID, HID);
    }
    {
        dim3 grid((N + 63) / 64, EMB / 64);
        gemm_bf16<64, 0, false><<<grid, 256, 0, stream>>>(prm.bufB, prm.w3bf, nullptr, prm.bufA,
                                                          N, HID, EMB);
    }
    k_agg<64, 1, 2><<<nb4, NTHR, 0, stream>>>(prm, prm.bufA, nullptr);
    k_final<<<(P + NTHR - 1) / NTHR, NTHR, 0, stream>>>(prm);
}